// Round 4
// baseline (225.641 us; speedup 1.0000x reference)
//
#include <hip/hip_runtime.h>

typedef float floatx4 __attribute__((ext_vector_type(4)));
typedef short shortx8 __attribute__((ext_vector_type(8)));

#define T_SEQ 2048
#define NQH   32
#define NKVH  8
#define HD    64
#define DM    2048
#define NTOT  3072

#if __has_builtin(__builtin_amdgcn_exp2f)
#define EXP2F(x) __builtin_amdgcn_exp2f(x)
#else
#define EXP2F(x) exp2f(x)
#endif

__device__ __forceinline__ unsigned short f2bf(float f) {
    unsigned int u = __builtin_bit_cast(unsigned int, f);
    u += 0x7FFFu + ((u >> 16) & 1u);          // RNE
    return (unsigned short)(u >> 16);
}
__device__ __forceinline__ unsigned int pk2bf(float a, float b) {
    return (unsigned int)f2bf(a) | ((unsigned int)f2bf(b) << 16);
}

// v_cvt_pk_bf16_f32: dst = {lo16=bf16(lo), hi16=bf16(hi)}, RNE, 1 instr
__device__ __forceinline__ unsigned int cvtpk_bf16(float lo, float hi) {
    unsigned int r;
    asm("v_cvt_pk_bf16_f32 %0, %1, %2" : "=v"(r) : "v"(lo), "v"(hi));
    return r;
}

// async global->LDS, 16B per lane; LDS dest = wave-uniform base + lane*16
__device__ __forceinline__ void dma16(const unsigned short* g, unsigned short* l) {
    __builtin_amdgcn_global_load_lds(
        (const __attribute__((address_space(1))) unsigned int*)g,
        (__attribute__((address_space(3))) unsigned int*)l,
        16, 0, 0);
}

// ---------------------------------------------------------------------------
// Fused conversion: blocks [0,4096) convert x fp32->bf16 (into d_out scratch);
// blocks [4096, 4096+1536) transpose-convert W -> Wt [n][k] bf16.
// ---------------------------------------------------------------------------
__global__ __launch_bounds__(256) void cvt_fused(
    const float* __restrict__ x, const float* __restrict__ Wq,
    const float* __restrict__ Wk, const float* __restrict__ Wv,
    unsigned short* __restrict__ xb, unsigned short* __restrict__ wt)
{
    __shared__ __align__(16) unsigned short Ts[64][72];
    const int id = blockIdx.x;
    const int t = threadIdx.x;
    if (id < 4096) {
        size_t i = ((size_t)id * 256 + t) * 8;
        float4 a = *(const float4*)(x + i);
        float4 b = *(const float4*)(x + i + 4);
        uint4 o;
        o.x = pk2bf(a.x, a.y); o.y = pk2bf(a.z, a.w);
        o.z = pk2bf(b.x, b.y); o.w = pk2bf(b.z, b.w);
        *(uint4*)(xb + i) = o;
        return;
    }
    const int id2 = id - 4096;
    const int k0 = (id2 & 31) * 64, n0g = (id2 >> 5) * 64;
    const float* W; int ldW, col0;
    if (n0g < 2048)      { W = Wq; ldW = 2048; col0 = n0g; }
    else if (n0g < 2560) { W = Wk; ldW = 512;  col0 = n0g - 2048; }
    else                 { W = Wv; ldW = 512;  col0 = n0g - 2560; }
    {
        int r = t >> 2, c = (t & 3) * 16;
        const float* src = W + (size_t)(k0 + r) * ldW + col0 + c;
        float4 v0 = *(const float4*)(src);
        float4 v1 = *(const float4*)(src + 4);
        float4 v2 = *(const float4*)(src + 8);
        float4 v3 = *(const float4*)(src + 12);
        uint4 o0 = {pk2bf(v0.x, v0.y), pk2bf(v0.z, v0.w), pk2bf(v1.x, v1.y), pk2bf(v1.z, v1.w)};
        uint4 o1 = {pk2bf(v2.x, v2.y), pk2bf(v2.z, v2.w), pk2bf(v3.x, v3.y), pk2bf(v3.z, v3.w)};
        *(uint4*)&Ts[r][c]     = o0;
        *(uint4*)&Ts[r][c + 8] = o1;
    }
    __syncthreads();
    {
        int n = t >> 2, kc = (t & 3) * 16;
        unsigned int dw[8];
        #pragma unroll
        for (int i = 0; i < 8; i++)
            dw[i] = (unsigned int)Ts[kc + 2 * i][n] | ((unsigned int)Ts[kc + 2 * i + 1][n] << 16);
        uint4 o0 = {dw[0], dw[1], dw[2], dw[3]}, o1 = {dw[4], dw[5], dw[6], dw[7]};
        unsigned short* d = wt + (size_t)(n0g + n) * DM + k0 + kc;
        *(uint4*)d = o0; *(uint4*)(d + 8) = o1;
    }
}

// ---------------------------------------------------------------------------
// Fused QKV GEMM. BM=256 x BN=192, BK=64, grid 256 = 1 block/CU (no tail).
// 8 waves (2M x 4N), per-wave 128x48. LDS 112 KiB double-buffered.
// R4: ONE barrier per K-tile (R3's 4 phase-barriers were unnecessary: all
// intra-tile reads hit buf cur, all DMA writes hit buf nb -> no intra-tile
// cross-wave hazard; the lockstep they forced was the regression). All 7
// DMAs for tile t+1 issued at the TOP of tile t -> full-tile slack (~780ns
// >> HBM latency), so the boundary vmcnt(0) finds the queue already drained.
// A-fragment ds_reads pipelined one quadrant ahead (named afA/afB sets).
// ---------------------------------------------------------------------------
__global__ __launch_bounds__(512, 2) void qkv_gemm(
    const unsigned short* __restrict__ xb,   // [4096][2048]
    const unsigned short* __restrict__ wt,   // [3072][2048]
    unsigned short* __restrict__ Qws, unsigned short* __restrict__ Kws,
    unsigned short* __restrict__ Vws)
{
    __shared__ __align__(16) unsigned short At[2][256 * 64];   // 64 KiB
    __shared__ __align__(16) unsigned short Bt[2][192 * 64];   // 48 KiB

    const int tid = threadIdx.x;
    const int wave = tid >> 6, lane = tid & 63;
    const int l16 = lane & 15, qd = lane >> 4;
    const int wm = wave >> 2, wn = wave & 3;    // 2M x 4N wave grid

    // bijective XCD swizzle: 256 blocks, 8 XCDs x 32 contiguous wgids.
    const int id  = blockIdx.x;                 // 0..255
    const int xcd = id & 7, j = id >> 3;
    const int wg  = xcd * 32 + j;
    const int mt  = wg >> 4, nt = wg & 15;
    const int m0 = mt * 256, n0g = nt * 192;

    const int lrow = lane >> 3;
    const int cgw  = (lane & 7) ^ lrow;            // DMA global col-group swizzle
    const int cg0  = (qd ^ (l16 & 7)) * 8;         // frag col offset, ks=0
    const int cg1  = ((4 | qd) ^ (l16 & 7)) * 8;   // ks=1

    floatx4 acc[8][3];
    #pragma unroll
    for (int mi = 0; mi < 8; mi++)
        #pragma unroll
        for (int ni = 0; ni < 3; ni++)
            acc[mi][ni] = (floatx4){0.f, 0.f, 0.f, 0.f};

    // per-thread global staging bases; per-wave LDS bases (uniform in wave)
    const unsigned short* gA = xb + (size_t)(m0 + wave * 8 + lrow) * DM + cgw * 8;
    const unsigned short* gB = wt + (size_t)(n0g + wave * 8 + lrow) * DM + cgw * 8;

#define DMA_A(s, kt, b) dma16(gA + (size_t)(s) * 64 * DM + (kt) * 64, \
                              &At[b][(s) * 4096 + wave * 512])
#define DMA_B(s, kt, b) dma16(gB + (size_t)(s) * 64 * DM + (kt) * 64, \
                              &Bt[b][(s) * 4096 + wave * 512])

    // prologue: tile 0 into buffer 0
    DMA_B(0, 0, 0); DMA_B(1, 0, 0); DMA_B(2, 0, 0);
    DMA_A(0, 0, 0); DMA_A(1, 0, 0); DMA_A(2, 0, 0); DMA_A(3, 0, 0);

    shortx8 bfr[3][2], afA[2][2], afB[2][2];

#define LOAD_B() { _Pragma("unroll") for (int nf = 0; nf < 3; nf++) { \
    const int bn = (wn * 48 + nf * 16 + l16) * 64; \
    bfr[nf][0] = *(const shortx8*)&Bt[cur][bn + cg0]; \
    bfr[nf][1] = *(const shortx8*)&Bt[cur][bn + cg1]; } }

#define LOAD_A(dst, q) { _Pragma("unroll") for (int mf = 0; mf < 2; mf++) { \
    const int ar = (wm * 128 + (q) * 32 + mf * 16 + l16) * 64; \
    dst[mf][0] = *(const shortx8*)&At[cur][ar + cg0]; \
    dst[mf][1] = *(const shortx8*)&At[cur][ar + cg1]; } }

#define MFMA_Q(q, src) { __builtin_amdgcn_s_setprio(1); \
    _Pragma("unroll") for (int mf = 0; mf < 2; mf++) \
    _Pragma("unroll") for (int nf = 0; nf < 3; nf++) { \
        acc[(q) * 2 + mf][nf] = __builtin_amdgcn_mfma_f32_16x16x32_bf16( \
            src[mf][0], bfr[nf][0], acc[(q) * 2 + mf][nf], 0, 0, 0); \
        acc[(q) * 2 + mf][nf] = __builtin_amdgcn_mfma_f32_16x16x32_bf16( \
            src[mf][1], bfr[nf][1], acc[(q) * 2 + mf][nf], 0, 0, 0); } \
    __builtin_amdgcn_s_setprio(0); }

    int cur = 0;
    for (int kt = 0; kt < 32; ++kt) {
        const bool pf = (kt < 31);
        const int nb = cur ^ 1;

        // tile boundary: own DMAs (issued a full tile ago) drained, then
        // publish all waves' writes to buf cur via barrier.
        asm volatile("s_waitcnt vmcnt(0)" ::: "memory");
        __builtin_amdgcn_s_barrier();
        asm volatile("" ::: "memory");

        // issue ALL of tile t+1 now: maximal latency slack, buf nb is free
        // (its readers finished before the barrier we just crossed).
        if (pf) {
            DMA_B(0, kt + 1, nb); DMA_B(1, kt + 1, nb); DMA_B(2, kt + 1, nb);
            DMA_A(0, kt + 1, nb); DMA_A(1, kt + 1, nb);
            DMA_A(2, kt + 1, nb); DMA_A(3, kt + 1, nb);
        }

        // compute tile t, A-fragments pipelined one quadrant ahead
        LOAD_B();
        LOAD_A(afA, 0);
        LOAD_A(afB, 1);
        MFMA_Q(0, afA);
        LOAD_A(afA, 2);
        MFMA_Q(1, afB);
        LOAD_A(afB, 3);
        MFMA_Q(2, afA);
        MFMA_Q(3, afB);

        cur = nb;
    }

    // ---- epilogue: per-element Q/K/V routing (192 doesn't divide 2048) ----
    const float qsc = 0.125f * 1.44269504f;
    #pragma unroll
    for (int q = 0; q < 4; q++)
        #pragma unroll
        for (int mf = 0; mf < 2; mf++)
            #pragma unroll
            for (int nf = 0; nf < 3; nf++)
                #pragma unroll
                for (int r = 0; r < 4; r++) {
                    int m   = m0 + wm * 128 + q * 32 + mf * 16 + qd * 4 + r;
                    int ncg = n0g + wn * 48 + nf * 16 + l16;
                    int b   = m >> 11, t = m & (T_SEQ - 1);
                    float v = acc[q * 2 + mf][nf][r];
                    if (ncg < 2048) {
                        int hh = ncg >> 6, d = ncg & 63;
                        Qws[((((size_t)b * NQH + hh) * T_SEQ + t) << 6) + d] = f2bf(v * qsc);
                    } else if (ncg < 2560) {
                        int nc = ncg - 2048, hh = nc >> 6, d = nc & 63;
                        Kws[((((size_t)b * NKVH + hh) * T_SEQ + t) << 6) + d] = f2bf(v);
                    } else {
                        int nc = ncg - 2560, hh = nc >> 6, d = nc & 63;
                        Vws[((((size_t)b * NKVH + hh) * HD + d) << 11) + t] = f2bf(v);
                    }
                }
#undef DMA_A
#undef DMA_B
#undef LOAD_B
#undef LOAD_A
#undef MFMA_Q
}

// ---------------------------------------------------------------------------
// Causal GQA flash attention, transposed form: S^T = K Q^T, O^T = V^T P^T.
// 8 waves x 512 threads; row-sum fused into an all-ones MFMA; P pack via
// v_cvt_pk_bf16_f32; diag-chunk wave-half skip; setprio(1) around PV.
// ---------------------------------------------------------------------------
__global__ __launch_bounds__(512, 4) void attn_fwd(
    const unsigned short* __restrict__ Qws,
    const unsigned short* __restrict__ Kws,
    const unsigned short* __restrict__ Vtws,
    float* __restrict__ out)
{
    __shared__ __align__(16) unsigned short Ks[2][64 * 64];
    __shared__ __align__(16) unsigned short Vt[2][64 * 64];
    __shared__ __align__(16) unsigned short Ps[8][32][40];   // per-wave [q in 32][key in 32-window]

    const int tid = threadIdx.x;
    const int wave = tid >> 6, lane = tid & 63;
    const int whead = wave & 3, wrow = wave >> 2;
    const int l16 = lane & 15, qd = lane >> 4;
    const int b = blockIdx.z;
    const int qt = b ? blockIdx.x : (31 - blockIdx.x);   // CU-pair makespan balance
    const int kh = blockIdx.y;
    const int h = kh * 4 + whead;
    const int q0 = qt * 64;
    const int mh = wrow * 32;

    const size_t qbase  = (((size_t)b * NQH + h) * T_SEQ + q0) * HD;
    const size_t kbase  = ((size_t)b * NKVH + kh) * (size_t)T_SEQ * HD;
    const size_t vtbase = ((size_t)b * NKVH + kh) * (size_t)HD * T_SEQ;

    // Q fragments (B operand), 32 rows per wave
    shortx8 qfr[2][2];
    #pragma unroll
    for (int mqt = 0; mqt < 2; mqt++)
        #pragma unroll
        for (int ks = 0; ks < 2; ks++)
            qfr[mqt][ks] = *(const shortx8*)(Qws + qbase +
                (size_t)(mh + mqt * 16 + l16) * HD + ks * 32 + qd * 8);

    const shortx8 ones = {0x3F80, 0x3F80, 0x3F80, 0x3F80,
                          0x3F80, 0x3F80, 0x3F80, 0x3F80};  // bf16 1.0

    floatx4 oaccT[2][4];      // [mqt][dt]: O^T tile, col q = l16, rows d = qd*4+r
    #pragma unroll
    for (int mqt = 0; mqt < 2; mqt++)
        #pragma unroll
        for (int dt = 0; dt < 4; dt++)
            oaccT[mqt][dt] = (floatx4){0.f, 0.f, 0.f, 0.f};
    floatx4 psum[2];          // ones^T P^T: every element = full row-sum for q=l16
    psum[0] = (floatx4){0.f, 0.f, 0.f, 0.f};
    psum[1] = (floatx4){0.f, 0.f, 0.f, 0.f};

    const int lrow = lane >> 3;
    const int cgw  = (lane & 7) ^ lrow;
    const int xr   = l16 & 7;
    const int rb   = wave * 8;     // 8 waves x 8 rows = 64 rows per buffer

    // prologue: stage chunk 0 into buffer 0
    dma16(Kws  + kbase  + (size_t)(rb + lrow) * HD + cgw * 8, &Ks[0][rb * 64]);
    dma16(Vtws + vtbase + (size_t)(rb + lrow) * T_SEQ + cgw * 8, &Vt[0][rb * 64]);

    for (int c = 0; c <= qt; c++) {
        const int cur = c & 1;
        __syncthreads();          // chunk c landed; buffer cur^1 free
        if (c < qt) {
            const int j0n = (c + 1) * 64;
            dma16(Kws  + kbase  + (size_t)(j0n + rb + lrow) * HD + cgw * 8,
                  &Ks[cur ^ 1][rb * 64]);
            dma16(Vtws + vtbase + (size_t)(rb + lrow) * T_SEQ + j0n + cgw * 8,
                  &Vt[cur ^ 1][rb * 64]);
        }

        const bool diag = (c == qt);

        #pragma unroll
        for (int kp = 0; kp < 2; kp++) {
            // diag chunk, row-half 0: keys 32..63 all > q rows 0..31 -> skip
            if (!(diag && wrow == 0 && kp == 1)) {
                // K fragments (A operand) for this 32-key window
                shortx8 kf[2][2];
                #pragma unroll
                for (int ktl = 0; ktl < 2; ktl++) {
                    const int krow = ((kp * 2 + ktl) * 16 + l16) * 64;
                    kf[ktl][0] = *(const shortx8*)&Ks[cur][krow + ((qd ^ xr) * 8)];
                    kf[ktl][1] = *(const shortx8*)&Ks[cur][krow + (((4 | qd) ^ xr) * 8)];
                }

                const bool msk = diag && (wrow == kp);   // diag window straddles row-half

                // ---- S^T = K Q^T, P = 2^S (bf16 RNE via cvt_pk), spill b64 ----
                #pragma unroll
                for (int ktl = 0; ktl < 2; ktl++) {
                    #pragma unroll
                    for (int mqt = 0; mqt < 2; mqt++) {
                        floatx4 s = (floatx4){0.f, 0.f, 0.f, 0.f};
                        s = __builtin_amdgcn_mfma_f32_16x16x32_bf16(kf[ktl][0], qfr[mqt][0], s, 0, 0, 0);
                        s = __builtin_amdgcn_mfma_f32_16x16x32_bf16(kf[ktl][1], qfr[mqt][1], s, 0, 0, 0);
                        float pe[4];
                        #pragma unroll
                        for (int r = 0; r < 4; r++) pe[r] = EXP2F(s[r]);
                        if (msk) {
                            const int qrel  = mh + mqt * 16 + l16;
                            const int jbase = kp * 32 + ktl * 16 + qd * 4;
                            #pragma unroll
                            for (int r = 0; r < 4; r++)
                                if (jbase + r > qrel) pe[r] = 0.f;
                        }
                        uint2 dw;
                        dw.x = cvtpk_bf16(pe[0], pe[1]);
                        dw.y = cvtpk_bf16(pe[2], pe[3]);
                        *(uint2*)&Ps[wave][mqt * 16 + l16][ktl * 16 + qd * 4] = dw;
                    }
                }

                // ---- P^T fragments (B operand; same-wave LDS round trip) ----
                shortx8 pfr[2];
                #pragma unroll
                for (int mqt = 0; mqt < 2; mqt++)
                    pfr[mqt] = *(const shortx8*)&Ps[wave][mqt * 16 + l16][qd * 8];

                // ---- row-sum fused as MFMA: psum += 1 * P^T ----
                #pragma unroll
                for (int mqt = 0; mqt < 2; mqt++)
                    psum[mqt] = __builtin_amdgcn_mfma_f32_16x16x32_bf16(
                        ones, pfr[mqt], psum[mqt], 0, 0, 0);

                // ---- O^T += V^T P^T ----
                __builtin_amdgcn_s_setprio(1);
                #pragma unroll
                for (int dt = 0; dt < 4; dt++) {
                    const shortx8 vf = *(const shortx8*)
                        &Vt[cur][(dt * 16 + l16) * 64 + (((kp * 4 + qd) ^ xr) * 8)];
                    #pragma unroll
                    for (int mqt = 0; mqt < 2; mqt++)
                        oaccT[mqt][dt] = __builtin_amdgcn_mfma_f32_16x16x32_bf16(
                            vf, pfr[mqt], oaccT[mqt][dt], 0, 0, 0);
                }
                __builtin_amdgcn_s_setprio(0);
            }
        }
    }

    // psum rows are identical (A = ones) -> denominator lane-local, no shuffles
    float inv[2];
    inv[0] = 1.f / psum[0][0];
    inv[1] = 1.f / psum[1][0];

    // ---- epilogue: O^T C-layout (col q = l16, rows d = qd*4+r) -> float4 ----
    #pragma unroll
    for (int mqt = 0; mqt < 2; mqt++) {
        const int t = q0 + mh + mqt * 16 + l16;
        float* orow = out + ((size_t)b * T_SEQ + t) * (NQH * HD) + h * HD + qd * 4;
        #pragma unroll
        for (int dt = 0; dt < 4; dt++) {
            float4 o;
            o.x = oaccT[mqt][dt][0] * inv[mqt];
            o.y = oaccT[mqt][dt][1] * inv[mqt];
            o.z = oaccT[mqt][dt][2] * inv[mqt];
            o.w = oaccT[mqt][dt][3] * inv[mqt];
            *(float4*)(orow + dt * 16) = o;
        }
    }
}

extern "C" void kernel_launch(void* const* d_in, const int* in_sizes, int n_in,
                              void* d_out, int out_size, void* d_ws, size_t ws_size,
                              hipStream_t stream) {
    const float* x  = (const float*)d_in[0];
    const float* Wq = (const float*)d_in[1];
    const float* Wk = (const float*)d_in[2];
    const float* Wv = (const float*)d_in[3];
    float* out = (float*)d_out;

    // xb scratch lives in d_out (16.8 MB of 33.5 MB) — dead before attn writes.
    unsigned short* xb  = (unsigned short*)d_out;
    unsigned short* wt  = (unsigned short*)d_ws;                  // 12.6 MB
    unsigned short* Qws = wt  + (size_t)NTOT * DM;                // 16.8 MB
    unsigned short* Kws = Qws + (size_t)2 * NQH * T_SEQ * HD;     // 4.2 MB
    unsigned short* Vws = Kws + (size_t)2 * NKVH * T_SEQ * HD;    // 4.2 MB

    cvt_fused<<<4096 + 1536, 256, 0, stream>>>(x, Wq, Wk, Wv, xb, wt);
    qkv_gemm <<<256, 512, 0, stream>>>(xb, wt, Qws, Kws, Vws);
    attn_fwd <<<dim3(32, NKVH, 2), 512, 0, stream>>>(Qws, Kws, Vws, out);
}

// Round 5
// 205.637 us; speedup vs baseline: 1.0973x; 1.0973x over previous
//
#include <hip/hip_runtime.h>

typedef float floatx4 __attribute__((ext_vector_type(4)));
typedef short shortx8 __attribute__((ext_vector_type(8)));

#define T_SEQ 2048
#define NQH   32
#define NKVH  8
#define HD    64
#define DM    2048
#define NTOT  3072

#if __has_builtin(__builtin_amdgcn_exp2f)
#define EXP2F(x) __builtin_amdgcn_exp2f(x)
#else
#define EXP2F(x) exp2f(x)
#endif

__device__ __forceinline__ unsigned short f2bf(float f) {
    unsigned int u = __builtin_bit_cast(unsigned int, f);
    u += 0x7FFFu + ((u >> 16) & 1u);          // RNE
    return (unsigned short)(u >> 16);
}
__device__ __forceinline__ unsigned int pk2bf(float a, float b) {
    return (unsigned int)f2bf(a) | ((unsigned int)f2bf(b) << 16);
}

// v_cvt_pk_bf16_f32: dst = {lo16=bf16(lo), hi16=bf16(hi)}, RNE, 1 instr
__device__ __forceinline__ unsigned int cvtpk_bf16(float lo, float hi) {
    unsigned int r;
    asm("v_cvt_pk_bf16_f32 %0, %1, %2" : "=v"(r) : "v"(lo), "v"(hi));
    return r;
}

// async global->LDS, 16B per lane; LDS dest = wave-uniform base + lane*16
__device__ __forceinline__ void dma16(const unsigned short* g, unsigned short* l) {
    __builtin_amdgcn_global_load_lds(
        (const __attribute__((address_space(1))) unsigned int*)g,
        (__attribute__((address_space(3))) unsigned int*)l,
        16, 0, 0);
}

// ---------------------------------------------------------------------------
// Fused conversion: blocks [0,4096) convert x fp32->bf16 (into d_out scratch);
// blocks [4096, 4096+1536) transpose-convert W -> Wt [n][k] bf16.
// R5 transpose: scatter-on-write / coalesce-on-read with XOR granule swizzle.
// Old version read columns as 16 ds_read_u16 at 8-way bank conflict (16-row
// stride x 144B = 2304B == 0 mod 128 -> 4 kc-groups alias onto 8 banks).
// New: phase 1 writes k-pairs as ds_write_b32 at physical granule
// (k>>3)^((n>>3)&7)  -> 32 banks, 2 lanes/bank (free); phase 2 reads rows as
// full-rate ds_read_b128 (8 granule slots evenly covered per wave).
// ---------------------------------------------------------------------------
__global__ __launch_bounds__(256) void cvt_fused(
    const float* __restrict__ x, const float* __restrict__ Wq,
    const float* __restrict__ Wk, const float* __restrict__ Wv,
    unsigned short* __restrict__ xb, unsigned short* __restrict__ wt)
{
    __shared__ __align__(16) unsigned short Ts[64 * 64];   // logical [n][k], swizzled
    const int id = blockIdx.x;
    const int t = threadIdx.x;
    if (id < 4096) {
        size_t i = ((size_t)id * 256 + t) * 8;
        float4 a = *(const float4*)(x + i);
        float4 b = *(const float4*)(x + i + 4);
        uint4 o;
        o.x = pk2bf(a.x, a.y); o.y = pk2bf(a.z, a.w);
        o.z = pk2bf(b.x, b.y); o.w = pk2bf(b.z, b.w);
        *(uint4*)(xb + i) = o;
        return;
    }
    const int id2 = id - 4096;
    const int k0 = (id2 & 31) * 64, n0g = (id2 >> 5) * 64;
    const float* W; int ldW, col0;
    if (n0g < 2048)      { W = Wq; ldW = 2048; col0 = n0g; }
    else if (n0g < 2560) { W = Wk; ldW = 512;  col0 = n0g - 2048; }
    else                 { W = Wv; ldW = 512;  col0 = n0g - 2560; }
    {
        // thread: k rows {2R, 2R+1}, n cols C..C+7
        const int R = t >> 3, C = (t & 7) * 8;
        const float* src0 = W + (size_t)(k0 + 2 * R) * ldW + col0 + C;
        const float* src1 = src0 + ldW;
        float4 a0 = *(const float4*)(src0);
        float4 a1 = *(const float4*)(src0 + 4);
        float4 b0 = *(const float4*)(src1);
        float4 b1 = *(const float4*)(src1 + 4);
        float lo[8] = {a0.x, a0.y, a0.z, a0.w, a1.x, a1.y, a1.z, a1.w};
        float hi[8] = {b0.x, b0.y, b0.z, b0.w, b1.x, b1.y, b1.z, b1.w};
        const int g = R >> 2;                 // granule of k=2R
        const int ko = (2 * R) & 7;           // short offset within granule (even)
        #pragma unroll
        for (int i = 0; i < 8; i++) {
            const int n = C + i;
            const int gp = g ^ ((n >> 3) & 7);
            *(unsigned int*)&Ts[n * 64 + gp * 8 + ko] = pk2bf(lo[i], hi[i]);
        }
    }
    __syncthreads();
    {
        const int n = t >> 2, kc = (t & 3) * 16;
        const int f = (n >> 3) & 7;
        const int g0 = kc >> 3;
        uint4 o0 = *(const uint4*)&Ts[n * 64 + ((g0)     ^ f) * 8];
        uint4 o1 = *(const uint4*)&Ts[n * 64 + ((g0 + 1) ^ f) * 8];
        unsigned short* d = wt + (size_t)(n0g + n) * DM + k0 + kc;
        *(uint4*)d = o0; *(uint4*)(d + 8) = o1;
    }
}

// ---------------------------------------------------------------------------
// Fused QKV GEMM, all-bf16, SINGLE-buffered LDS (m97 structure: 2 barriers
// per K-step). 32 KiB LDS -> one dispatch round at 768 blocks. Proven 60.7us
// (R2); R3/R4 deep-pipeline variants both regressed (72/80us) -> reverted.
// ---------------------------------------------------------------------------
__global__ __launch_bounds__(256, 4) void qkv_gemm(
    const unsigned short* __restrict__ xb,   // [4096][2048]
    const unsigned short* __restrict__ wt,   // [3072][2048]
    unsigned short* __restrict__ Qws, unsigned short* __restrict__ Kws,
    unsigned short* __restrict__ Vws)
{
    __shared__ __align__(16) unsigned short At[128 * 64];
    __shared__ __align__(16) unsigned short Bt[128 * 64];

    const int tid = threadIdx.x;
    const int wave = tid >> 6, lane = tid & 63;
    const int l16 = lane & 15, qd = lane >> 4;

    const int id  = blockIdx.y * 24 + blockIdx.x;       // 0..767
    const int xcd = id & 7, j = id >> 3;                // j 0..95
    const int m0 = (xcd * 4 + (j & 3)) * 128;           // 32 m-tiles
    const int n0 = (j >> 2) * 128;                      // 24 n-tiles

    const int mh = (wave >> 1) * 64, nh = (wave & 1) * 64;

    const int lrow = lane >> 3;
    const int cgw  = (lane & 7) ^ lrow;            // DMA global col-group swizzle
    const int cg0  = (qd ^ (l16 & 7)) * 8;         // frag col offset, ks=0
    const int cg1  = ((4 | qd) ^ (l16 & 7)) * 8;   // ks=1

    floatx4 acc[4][4];
    #pragma unroll
    for (int mi = 0; mi < 4; mi++)
        #pragma unroll
        for (int ni = 0; ni < 4; ni++)
            acc[mi][ni] = (floatx4){0.f, 0.f, 0.f, 0.f};

    size_t gA[4], gB[4];
    int lofs[4];
    #pragma unroll
    for (int jj = 0; jj < 4; jj++) {
        const int rb = wave * 32 + jj * 8;
        gA[jj] = (size_t)(m0 + rb + lrow) * DM + cgw * 8;
        gB[jj] = (size_t)(n0 + rb + lrow) * DM + cgw * 8;
        lofs[jj] = rb * 64;
    }

    // prologue: stage tile 0
    #pragma unroll
    for (int jj = 0; jj < 4; jj++) {
        dma16(xb + gA[jj], &At[lofs[jj]]);
        dma16(wt + gB[jj], &Bt[lofs[jj]]);
    }

    for (int k0 = 0; k0 < DM; k0 += 64) {
        __syncthreads();          // vmcnt(0) drained before barrier -> tile k0 landed
        #pragma unroll
        for (int ks = 0; ks < 2; ks++) {
            const int cg = ks ? cg1 : cg0;
            shortx8 af[4], bfr[4];
            #pragma unroll
            for (int i = 0; i < 4; i++) {
                af[i]  = *(const shortx8*)&At[(mh + i * 16 + l16) * 64 + cg];
                bfr[i] = *(const shortx8*)&Bt[(nh + i * 16 + l16) * 64 + cg];
            }
            #pragma unroll
            for (int mi = 0; mi < 4; mi++)
                #pragma unroll
                for (int ni = 0; ni < 4; ni++)
                    acc[mi][ni] = __builtin_amdgcn_mfma_f32_16x16x32_bf16(
                        af[mi], bfr[ni], acc[mi][ni], 0, 0, 0);
        }
        __syncthreads();          // all waves done reading LDS
        if (k0 + 64 < DM) {
            #pragma unroll
            for (int jj = 0; jj < 4; jj++) {
                dma16(xb + gA[jj] + k0 + 64, &At[lofs[jj]]);
                dma16(wt + gB[jj] + k0 + 64, &Bt[lofs[jj]]);
            }
        }
    }

    int ncol, H; unsigned short* dst; float sc; bool vtrans;
    if (n0 < 2048)      { ncol = n0;        dst = Qws; H = NQH;  sc = 0.125f * 1.44269504f; vtrans = false; }
    else if (n0 < 2560) { ncol = n0 - 2048; dst = Kws; H = NKVH; sc = 1.0f; vtrans = false; }
    else                { ncol = n0 - 2560; dst = Vws; H = NKVH; sc = 1.0f; vtrans = true;  }

    #pragma unroll
    for (int mi = 0; mi < 4; mi++)
        #pragma unroll
        for (int ni = 0; ni < 4; ni++)
            #pragma unroll
            for (int r = 0; r < 4; r++) {
                int m  = m0 + mh + mi * 16 + qd * 4 + r;
                int nc = ncol + nh + ni * 16 + l16;
                int b  = m >> 11, t = m & (T_SEQ - 1);
                int hh = nc >> 6, d = nc & 63;
                float v = acc[mi][ni][r] * sc;
                size_t idx = vtrans
                    ? ((((size_t)b * H + hh) * HD + d) << 11) + t
                    : ((((size_t)b * H + hh) * T_SEQ + t) << 6) + d;
                dst[idx] = f2bf(v);
            }
}

// ---------------------------------------------------------------------------
// Causal GQA flash attention, transposed form: S^T = K Q^T, O^T = V^T P^T.
// 8 waves x 512 threads; row-sum fused into an all-ones MFMA; P pack via
// v_cvt_pk_bf16_f32; diag-chunk wave-half skip; setprio(1) around PV.
// ---------------------------------------------------------------------------
__global__ __launch_bounds__(512, 4) void attn_fwd(
    const unsigned short* __restrict__ Qws,
    const unsigned short* __restrict__ Kws,
    const unsigned short* __restrict__ Vtws,
    float* __restrict__ out)
{
    __shared__ __align__(16) unsigned short Ks[2][64 * 64];
    __shared__ __align__(16) unsigned short Vt[2][64 * 64];
    __shared__ __align__(16) unsigned short Ps[8][32][40];   // per-wave [q in 32][key in 32-window]

    const int tid = threadIdx.x;
    const int wave = tid >> 6, lane = tid & 63;
    const int whead = wave & 3, wrow = wave >> 2;
    const int l16 = lane & 15, qd = lane >> 4;
    const int b = blockIdx.z;
    const int qt = b ? blockIdx.x : (31 - blockIdx.x);   // CU-pair makespan balance
    const int kh = blockIdx.y;
    const int h = kh * 4 + whead;
    const int q0 = qt * 64;
    const int mh = wrow * 32;

    const size_t qbase  = (((size_t)b * NQH + h) * T_SEQ + q0) * HD;
    const size_t kbase  = ((size_t)b * NKVH + kh) * (size_t)T_SEQ * HD;
    const size_t vtbase = ((size_t)b * NKVH + kh) * (size_t)HD * T_SEQ;

    // Q fragments (B operand), 32 rows per wave
    shortx8 qfr[2][2];
    #pragma unroll
    for (int mqt = 0; mqt < 2; mqt++)
        #pragma unroll
        for (int ks = 0; ks < 2; ks++)
            qfr[mqt][ks] = *(const shortx8*)(Qws + qbase +
                (size_t)(mh + mqt * 16 + l16) * HD + ks * 32 + qd * 8);

    const shortx8 ones = {0x3F80, 0x3F80, 0x3F80, 0x3F80,
                          0x3F80, 0x3F80, 0x3F80, 0x3F80};  // bf16 1.0

    floatx4 oaccT[2][4];      // [mqt][dt]: O^T tile, col q = l16, rows d = qd*4+r
    #pragma unroll
    for (int mqt = 0; mqt < 2; mqt++)
        #pragma unroll
        for (int dt = 0; dt < 4; dt++)
            oaccT[mqt][dt] = (floatx4){0.f, 0.f, 0.f, 0.f};
    floatx4 psum[2];          // ones^T P^T: every element = full row-sum for q=l16
    psum[0] = (floatx4){0.f, 0.f, 0.f, 0.f};
    psum[1] = (floatx4){0.f, 0.f, 0.f, 0.f};

    const int lrow = lane >> 3;
    const int cgw  = (lane & 7) ^ lrow;
    const int xr   = l16 & 7;
    const int rb   = wave * 8;     // 8 waves x 8 rows = 64 rows per buffer

    // prologue: stage chunk 0 into buffer 0
    dma16(Kws  + kbase  + (size_t)(rb + lrow) * HD + cgw * 8, &Ks[0][rb * 64]);
    dma16(Vtws + vtbase + (size_t)(rb + lrow) * T_SEQ + cgw * 8, &Vt[0][rb * 64]);

    for (int c = 0; c <= qt; c++) {
        const int cur = c & 1;
        __syncthreads();          // chunk c landed; buffer cur^1 free
        if (c < qt) {
            const int j0n = (c + 1) * 64;
            dma16(Kws  + kbase  + (size_t)(j0n + rb + lrow) * HD + cgw * 8,
                  &Ks[cur ^ 1][rb * 64]);
            dma16(Vtws + vtbase + (size_t)(rb + lrow) * T_SEQ + j0n + cgw * 8,
                  &Vt[cur ^ 1][rb * 64]);
        }

        const bool diag = (c == qt);

        #pragma unroll
        for (int kp = 0; kp < 2; kp++) {
            // diag chunk, row-half 0: keys 32..63 all > q rows 0..31 -> skip
            if (!(diag && wrow == 0 && kp == 1)) {
                // K fragments (A operand) for this 32-key window
                shortx8 kf[2][2];
                #pragma unroll
                for (int ktl = 0; ktl < 2; ktl++) {
                    const int krow = ((kp * 2 + ktl) * 16 + l16) * 64;
                    kf[ktl][0] = *(const shortx8*)&Ks[cur][krow + ((qd ^ xr) * 8)];
                    kf[ktl][1] = *(const shortx8*)&Ks[cur][krow + (((4 | qd) ^ xr) * 8)];
                }

                const bool msk = diag && (wrow == kp);   // diag window straddles row-half

                // ---- S^T = K Q^T, P = 2^S (bf16 RNE via cvt_pk), spill b64 ----
                #pragma unroll
                for (int ktl = 0; ktl < 2; ktl++) {
                    #pragma unroll
                    for (int mqt = 0; mqt < 2; mqt++) {
                        floatx4 s = (floatx4){0.f, 0.f, 0.f, 0.f};
                        s = __builtin_amdgcn_mfma_f32_16x16x32_bf16(kf[ktl][0], qfr[mqt][0], s, 0, 0, 0);
                        s = __builtin_amdgcn_mfma_f32_16x16x32_bf16(kf[ktl][1], qfr[mqt][1], s, 0, 0, 0);
                        float pe[4];
                        #pragma unroll
                        for (int r = 0; r < 4; r++) pe[r] = EXP2F(s[r]);
                        if (msk) {
                            const int qrel  = mh + mqt * 16 + l16;
                            const int jbase = kp * 32 + ktl * 16 + qd * 4;
                            #pragma unroll
                            for (int r = 0; r < 4; r++)
                                if (jbase + r > qrel) pe[r] = 0.f;
                        }
                        uint2 dw;
                        dw.x = cvtpk_bf16(pe[0], pe[1]);
                        dw.y = cvtpk_bf16(pe[2], pe[3]);
                        *(uint2*)&Ps[wave][mqt * 16 + l16][ktl * 16 + qd * 4] = dw;
                    }
                }

                // ---- P^T fragments (B operand; same-wave LDS round trip) ----
                shortx8 pfr[2];
                #pragma unroll
                for (int mqt = 0; mqt < 2; mqt++)
                    pfr[mqt] = *(const shortx8*)&Ps[wave][mqt * 16 + l16][qd * 8];

                // ---- row-sum fused as MFMA: psum += 1 * P^T ----
                #pragma unroll
                for (int mqt = 0; mqt < 2; mqt++)
                    psum[mqt] = __builtin_amdgcn_mfma_f32_16x16x32_bf16(
                        ones, pfr[mqt], psum[mqt], 0, 0, 0);

                // ---- O^T += V^T P^T ----
                __builtin_amdgcn_s_setprio(1);
                #pragma unroll
                for (int dt = 0; dt < 4; dt++) {
                    const shortx8 vf = *(const shortx8*)
                        &Vt[cur][(dt * 16 + l16) * 64 + (((kp * 4 + qd) ^ xr) * 8)];
                    #pragma unroll
                    for (int mqt = 0; mqt < 2; mqt++)
                        oaccT[mqt][dt] = __builtin_amdgcn_mfma_f32_16x16x32_bf16(
                            vf, pfr[mqt], oaccT[mqt][dt], 0, 0, 0);
                }
                __builtin_amdgcn_s_setprio(0);
            }
        }
    }

    // psum rows are identical (A = ones) -> denominator lane-local, no shuffles
    float inv[2];
    inv[0] = 1.f / psum[0][0];
    inv[1] = 1.f / psum[1][0];

    // ---- epilogue: O^T C-layout (col q = l16, rows d = qd*4+r) -> float4 ----
    #pragma unroll
    for (int mqt = 0; mqt < 2; mqt++) {
        const int t = q0 + mh + mqt * 16 + l16;
        float* orow = out + ((size_t)b * T_SEQ + t) * (NQH * HD) + h * HD + qd * 4;
        #pragma unroll
        for (int dt = 0; dt < 4; dt++) {
            float4 o;
            o.x = oaccT[mqt][dt][0] * inv[mqt];
            o.y = oaccT[mqt][dt][1] * inv[mqt];
            o.z = oaccT[mqt][dt][2] * inv[mqt];
            o.w = oaccT[mqt][dt][3] * inv[mqt];
            *(float4*)(orow + dt * 16) = o;
        }
    }
}

extern "C" void kernel_launch(void* const* d_in, const int* in_sizes, int n_in,
                              void* d_out, int out_size, void* d_ws, size_t ws_size,
                              hipStream_t stream) {
    const float* x  = (const float*)d_in[0];
    const float* Wq = (const float*)d_in[1];
    const float* Wk = (const float*)d_in[2];
    const float* Wv = (const float*)d_in[3];
    float* out = (float*)d_out;

    // xb scratch lives in d_out (16.8 MB of 33.5 MB) — dead before attn writes.
    unsigned short* xb  = (unsigned short*)d_out;
    unsigned short* wt  = (unsigned short*)d_ws;                  // 12.6 MB
    unsigned short* Qws = wt  + (size_t)NTOT * DM;                // 16.8 MB
    unsigned short* Kws = Qws + (size_t)2 * NQH * T_SEQ * HD;     // 4.2 MB
    unsigned short* Vws = Kws + (size_t)2 * NKVH * T_SEQ * HD;    // 4.2 MB

    cvt_fused<<<4096 + 1536, 256, 0, stream>>>(x, Wq, Wk, Wv, xb, wt);
    qkv_gemm <<<dim3(24, 32), 256, 0, stream>>>(xb, wt, Qws, Kws, Vws);
    attn_fwd <<<dim3(32, NKVH, 2), 512, 0, stream>>>(Qws, Kws, Vws, out);
}